// Round 10
// baseline (189.640 us; speedup 1.0000x reference)
//
#include <hip/hip_runtime.h>
#include <hip/hip_bf16.h>
#include <math.h>

#define NUM_CLASSES 10
#define BATCH 2048
#define DIM 128
#define INV_T 14.285714285714286f   // 1/0.07; TEMPERATURE/BASE_TEMPERATURE = 1
#define NTILE 16                    // 2048/128 row stripes
#define NPAIR 136                   // upper-triangular 128x128 block pairs

typedef __attribute__((ext_vector_type(8))) short bf16x8;   // 8 bf16 = 4 VGPRs
typedef __attribute__((ext_vector_type(4))) float f32x4;    // MFMA accumulator

// Async 16B-per-lane global->LDS. LDS dest = wave-uniform base + lane*16.
__device__ __forceinline__ void load_lds16(const void* g, void* lds) {
    __builtin_amdgcn_global_load_lds(
        (const __attribute__((address_space(1))) unsigned int*)g,
        (__attribute__((address_space(3))) unsigned int*)lds,
        16, 0, 0);
}

// ---------------------------------------------------------------------------
// 1) Row-normalize preds -> bf16 g; fuse zeroing of denom/s2 accumulators
//    and the block-completion counter.
// ---------------------------------------------------------------------------
__global__ __launch_bounds__(256) void normalize_kernel(
    const float* __restrict__ preds, __hip_bfloat16* __restrict__ g,
    float* __restrict__ zero_buf, int* __restrict__ counter)
{
    int b = blockIdx.x;
    int t = threadIdx.x;
    if (t < 8) zero_buf[b * 8 + t] = 0.0f;   // 5120*8 = 40960 floats (denom+s2)
    if (b == 0 && t == 0) counter[0] = 0;

    int row  = b * 4 + (t >> 6);
    int lane = t & 63;
    const float2* src = (const float2*)(preds + (size_t)row * DIM);
    float2 v = src[lane];
    float ss = v.x * v.x + v.y * v.y;
#pragma unroll
    for (int m = 32; m; m >>= 1) ss += __shfl_xor(ss, m, 64);
    float rn = 1.0f / sqrtf(ss);
    __hip_bfloat162 o;
    o.x = __float2bfloat16(v.x * rn);
    o.y = __float2bfloat16(v.y * rn);
    *(__hip_bfloat162*)(g + (size_t)row * DIM + lane * 2) = o;
}

// ---------------------------------------------------------------------------
// 2) MFMA Gram (round-7 verified body: 64 KiB LDS, async global_load_lds,
//    XOR swizzle, merged den+sp epilogue) + FUSED finalize: the last block
//    to finish (device atomic counter, threadfence release/acquire) reduces
//    denom/s2 -> out.
// ---------------------------------------------------------------------------
__global__ __launch_bounds__(256) void gram_kernel(
    const __hip_bfloat16* __restrict__ g, const int* __restrict__ target,
    float* __restrict__ denom, float* __restrict__ s2,
    int* __restrict__ counter, const float* __restrict__ log_vars,
    float* __restrict__ out)
{
    // decode upper-tri pair (by <= bx)
    int p = blockIdx.x;
    int by = 0, rem = NTILE;
    while (p >= rem) { p -= rem; --rem; ++by; }
    const int bx   = by + p;
    const int cls  = blockIdx.y;
    const int row0 = by * 128;
    const int col0 = bx * 128;
    const bool isDiag = (by == bx);
    const ushort* gc = (const ushort*)g + (size_t)cls * BATCH * DIM;

    __shared__ __align__(16) ushort smem[2 * 128 * 128];   // 64 KiB
    ushort* As = smem;
    ushort* Bs = smem + 128 * 128;

    const int t    = threadIdx.x;
    const int wid  = t >> 6;
    const int lane = t & 63;
    const int tx   = lane & 15;         // C/D: col = lane&15; frag row sel
    const int quad = lane >> 4;         // C/D: row = quad*4 + reg
    const int wm   = (wid >> 1) * 64;
    const int wn   = (wid & 1) * 64;

    // ---- async staging: 8 (+8) global_load_lds_dwordx4 per thread ----
    const int lr = lane >> 4;           // row-within-4
    const int lp = lane & 15;           // chunk position 0..15
#pragma unroll
    for (int s = 0; s < 8; ++s) {
        int rb = s * 16 + wid * 4;      // wave-uniform row base
        int r  = rb + lr;
        int c  = lp ^ (r & 15);         // fetch chunk c into position lp
        load_lds16(gc + (size_t)(row0 + r) * DIM + c * 8, &As[rb * 128]);
        if (!isDiag)
            load_lds16(gc + (size_t)(col0 + r) * DIM + c * 8, &Bs[rb * 128]);
    }
    __syncthreads();   // drains vmcnt before LDS reads

    // ---- MFMA main loop: K=128 in 4 slices of 32 ----
    const ushort* BsR = isDiag ? As : Bs;
    f32x4 acc[4][4] = {};
#pragma unroll
    for (int ks = 0; ks < 4; ++ks) {
        bf16x8 af[4], bg[4];
#pragma unroll
        for (int i = 0; i < 4; ++i) {
            int pa = ((ks * 4 + quad) ^ tx) * 8;   // swizzled chunk offset
            af[i] = *(const bf16x8*)&As [(wm + i * 16 + tx) * 128 + pa];
            bg[i] = *(const bf16x8*)&BsR[(wn + i * 16 + tx) * 128 + pa];
        }
#pragma unroll
        for (int i = 0; i < 4; ++i)
#pragma unroll
            for (int j = 0; j < 4; ++j)
                acc[i][j] = __builtin_amdgcn_mfma_f32_16x16x32_bf16(
                    af[i], bg[j], acc[i][j], 0, 0, 0);
    }
    __syncthreads();   // all tile reads done; safe to reuse LDS

    // ---- epilogue: register partials -> LDS transpose -> atomics ----
    unsigned laMask = 0;
#pragma unroll
    for (int i = 0; i < 4; ++i)
#pragma unroll
        for (int r = 0; r < 4; ++r)
            if (target[row0 + wm + i * 16 + quad * 4 + r] == cls)
                laMask |= 1u << (i * 4 + r);
    int lb[4];
#pragma unroll
    for (int j = 0; j < 4; ++j) lb[j] = (target[col0 + wn + j * 16 + tx] == cls);

    float2* rbuf = (float2*)smem;                    // [wid][64 x17][tx] 34816 B
    float2* cbuf = (float2*)(smem + 17408);          // [wid][64 x5][quad] 10240 B
    float2 pcol[4] = {};

#pragma unroll
    for (int i = 0; i < 4; ++i) {
        float2 prow[4] = {};
#pragma unroll
        for (int j = 0; j < 4; ++j) {
            int cg = col0 + wn + j * 16 + tx;
            int lbj = lb[j];
#pragma unroll
            for (int r = 0; r < 4; ++r) {
                int rg = row0 + wm + i * 16 + quad * 4 + r;
                float logit = acc[i][j][r] * INV_T;
                float e = __expf(logit);
                bool dg = isDiag && (cg == rg);
                e = dg ? 0.0f : e;
                bool same = (((laMask >> (i * 4 + r)) & 1) == (unsigned)lbj) && !dg;
                float sl = same ? logit : 0.0f;
                prow[r].x += e; prow[r].y += sl;
                pcol[j].x += e; pcol[j].y += sl;
            }
        }
#pragma unroll
        for (int r = 0; r < 4; ++r)
            rbuf[wid * 1088 + (i * 16 + quad * 4 + r) * 17 + tx] = prow[r];
    }
#pragma unroll
    for (int j = 0; j < 4; ++j)
        cbuf[wid * 320 + (j * 16 + tx) * 5 + quad] = pcol[j];
    __syncthreads();

    if (t < 128) {
        // rows: wids 2*grp, 2*grp+1 share wm = 64*grp
        int rl = t & 63, grp = t >> 6;
        float den = 0.0f, sp = 0.0f;
#pragma unroll
        for (int w = 0; w < 2; ++w) {
            int base = (2 * grp + w) * 1088 + rl * 17;
#pragma unroll
            for (int x = 0; x < 16; ++x) {
                float2 v = rbuf[base + x];
                den += v.x; sp += v.y;
            }
        }
        atomicAdd(&denom[cls * BATCH + row0 + t], den);
        atomicAdd(&s2   [cls * BATCH + row0 + t], sp);
    } else if (!isDiag) {
        // cols: wids grp, grp+2 share wn = 64*grp
        int u = t - 128;
        int cl = u & 63, grp = u >> 6;
        float den = 0.0f, sp = 0.0f;
#pragma unroll
        for (int w = 0; w < 2; ++w) {
            int base = (grp + 2 * w) * 320 + cl * 5;
#pragma unroll
            for (int q = 0; q < 4; ++q) {
                float2 v = cbuf[base + q];
                den += v.x; sp += v.y;
            }
        }
        atomicAdd(&denom[cls * BATCH + col0 + u], den);
        atomicAdd(&s2   [cls * BATCH + col0 + u], sp);
    }

    // ---- fused finalize: last block to finish reduces denom/s2 -> out ----
    __shared__ int isLast;
    __threadfence();                       // release: data atomics before count
    if (t == 0) {
        int old = atomicAdd(counter, 1);
        isLast = (old == NPAIR * NUM_CLASSES - 1);
    }
    __syncthreads();
    if (!isLast) return;
    __threadfence();                       // acquire: see all blocks' atomics

    // per-class histogram of target (each thread covers 8 entries)
    int hist[NUM_CLASSES];
#pragma unroll
    for (int c = 0; c < NUM_CLASSES; ++c) hist[c] = 0;
#pragma unroll
    for (int k = 0; k < 8; ++k) ++hist[target[t * 8 + k]];
    __shared__ int chist[NUM_CLASSES * 4];
#pragma unroll
    for (int c = 0; c < NUM_CLASSES; ++c) {
        int v = hist[c];
#pragma unroll
        for (int m = 1; m < 64; m <<= 1) v += __shfl_xor(v, m, 64);
        if (lane == 0) chist[c * 4 + wid] = v;
    }
    __syncthreads();

    float part = 0.0f;
    for (int idx = t; idx < NUM_CLASSES * BATCH; idx += 256) {
        int c2 = idx >> 11;
        int a  = idx & (BATCH - 1);
        int c1 = chist[c2 * 4] + chist[c2 * 4 + 1] + chist[c2 * 4 + 2] + chist[c2 * 4 + 3];
        int la = (target[a] == c2);
        int cnt = la ? (c1 - 1) : (BATCH - c1 - 1);
        float mlpp = s2[idx] / (float)cnt - logf(denom[idx]);
        part += __expf(-log_vars[c2]) * mlpp;
    }
    __shared__ float wred[4];
#pragma unroll
    for (int m = 32; m; m >>= 1) part += __shfl_xor(part, m, 64);
    if (lane == 0) wred[wid] = part;
    __syncthreads();
    if (t == 0) {
        float lv = 0.0f;
        for (int i = 0; i < NUM_CLASSES; ++i) lv += log_vars[i];
        out[0] = lv - (wred[0] + wred[1] + wred[2] + wred[3]) / (float)BATCH;
    }
}

// ---------------------------------------------------------------------------
extern "C" void kernel_launch(void* const* d_in, const int* in_sizes, int n_in,
                              void* d_out, int out_size, void* d_ws, size_t ws_size,
                              hipStream_t stream)
{
    const float* preds    = (const float*)d_in[0];   // [10,2048,128] f32
    const int*   target   = (const int*)  d_in[1];   // [2048]
    const float* log_vars = (const float*)d_in[2];   // [10]
    float* out = (float*)d_out;

    __hip_bfloat16* gbf = (__hip_bfloat16*)d_ws;              // 10*2048*128 bf16
    float* denom  = (float*)((char*)d_ws + (size_t)NUM_CLASSES * BATCH * DIM * 2);
    float* s2     = denom + (size_t)NUM_CLASSES * BATCH;
    int*   counter = (int*)(s2 + (size_t)NUM_CLASSES * BATCH);

    normalize_kernel<<<NUM_CLASSES * BATCH / 4, 256, 0, stream>>>(
        preds, gbf, denom, counter);
    gram_kernel<<<dim3(NPAIR, NUM_CLASSES), 256, 0, stream>>>(
        gbf, target, denom, s2, counter, log_vars, out);
}

// Round 11
// 121.842 us; speedup vs baseline: 1.5564x; 1.5564x over previous
//
#include <hip/hip_runtime.h>
#include <hip/hip_bf16.h>
#include <math.h>

#define NUM_CLASSES 10
#define BATCH 2048
#define DIM 128
#define INV_T 14.285714285714286f   // 1/0.07; TEMPERATURE/BASE_TEMPERATURE = 1
#define NTILE 16                    // 2048/128 row stripes
#define NPAIR 136                   // upper-triangular 128x128 block pairs

typedef __attribute__((ext_vector_type(8))) short bf16x8;   // 8 bf16 = 4 VGPRs
typedef __attribute__((ext_vector_type(4))) float f32x4;    // MFMA accumulator

// Async 16B-per-lane global->LDS. LDS dest = wave-uniform base + lane*16.
__device__ __forceinline__ void load_lds16(const void* g, void* lds) {
    __builtin_amdgcn_global_load_lds(
        (const __attribute__((address_space(1))) unsigned int*)g,
        (__attribute__((address_space(3))) unsigned int*)lds,
        16, 0, 0);
}

// ---------------------------------------------------------------------------
// 1) Row-normalize preds -> bf16 g; fuse zeroing of denom/s2 accumulators
//    and the block-completion counter.
// ---------------------------------------------------------------------------
__global__ __launch_bounds__(256) void normalize_kernel(
    const float* __restrict__ preds, __hip_bfloat16* __restrict__ g,
    float* __restrict__ zero_buf, int* __restrict__ counter)
{
    int b = blockIdx.x;
    int t = threadIdx.x;
    if (t < 8) zero_buf[b * 8 + t] = 0.0f;   // 5120*8 = 40960 floats (denom+s2)
    if (b == 0 && t == 0) counter[0] = 0;

    int row  = b * 4 + (t >> 6);
    int lane = t & 63;
    const float2* src = (const float2*)(preds + (size_t)row * DIM);
    float2 v = src[lane];
    float ss = v.x * v.x + v.y * v.y;
#pragma unroll
    for (int m = 32; m; m >>= 1) ss += __shfl_xor(ss, m, 64);
    float rn = 1.0f / sqrtf(ss);
    __hip_bfloat162 o;
    o.x = __float2bfloat16(v.x * rn);
    o.y = __float2bfloat16(v.y * rn);
    *(__hip_bfloat162*)(g + (size_t)row * DIM + lane * 2) = o;
}

// ---------------------------------------------------------------------------
// 2) MFMA Gram (round-7 verified body: 64 KiB LDS, async global_load_lds,
//    XOR swizzle, merged den+sp epilogue) + fused finalize via last-block-
//    done. LDS kept at EXACTLY 65536 B (finalize scratch aliased into smem;
//    >64 KiB halves blocks/CU — round-10 lesson). Release ordering comes
//    from __syncthreads' vmcnt(0) drain; acquire fence only in last block.
// ---------------------------------------------------------------------------
__global__ __launch_bounds__(256) void gram_kernel(
    const __hip_bfloat16* __restrict__ g, const int* __restrict__ target,
    float* __restrict__ denom, float* __restrict__ s2,
    int* __restrict__ counter, const float* __restrict__ log_vars,
    float* __restrict__ out)
{
    // decode upper-tri pair (by <= bx)
    int p = blockIdx.x;
    int by = 0, rem = NTILE;
    while (p >= rem) { p -= rem; --rem; ++by; }
    const int bx   = by + p;
    const int cls  = blockIdx.y;
    const int row0 = by * 128;
    const int col0 = bx * 128;
    const bool isDiag = (by == bx);
    const ushort* gc = (const ushort*)g + (size_t)cls * BATCH * DIM;

    __shared__ __align__(16) ushort smem[2 * 128 * 128];   // exactly 65536 B
    ushort* As = smem;
    ushort* Bs = smem + 128 * 128;

    const int t    = threadIdx.x;
    const int wid  = t >> 6;
    const int lane = t & 63;
    const int tx   = lane & 15;         // C/D: col = lane&15; frag row sel
    const int quad = lane >> 4;         // C/D: row = quad*4 + reg
    const int wm   = (wid >> 1) * 64;
    const int wn   = (wid & 1) * 64;

    // ---- async staging: 8 (+8) global_load_lds_dwordx4 per thread ----
    const int lr = lane >> 4;           // row-within-4
    const int lp = lane & 15;           // chunk position 0..15
#pragma unroll
    for (int s = 0; s < 8; ++s) {
        int rb = s * 16 + wid * 4;      // wave-uniform row base
        int r  = rb + lr;
        int c  = lp ^ (r & 15);         // fetch chunk c into position lp
        load_lds16(gc + (size_t)(row0 + r) * DIM + c * 8, &As[rb * 128]);
        if (!isDiag)
            load_lds16(gc + (size_t)(col0 + r) * DIM + c * 8, &Bs[rb * 128]);
    }
    __syncthreads();   // drains vmcnt before LDS reads

    // ---- MFMA main loop: K=128 in 4 slices of 32 ----
    const ushort* BsR = isDiag ? As : Bs;
    f32x4 acc[4][4] = {};
#pragma unroll
    for (int ks = 0; ks < 4; ++ks) {
        bf16x8 af[4], bg[4];
#pragma unroll
        for (int i = 0; i < 4; ++i) {
            int pa = ((ks * 4 + quad) ^ tx) * 8;   // swizzled chunk offset
            af[i] = *(const bf16x8*)&As [(wm + i * 16 + tx) * 128 + pa];
            bg[i] = *(const bf16x8*)&BsR[(wn + i * 16 + tx) * 128 + pa];
        }
#pragma unroll
        for (int i = 0; i < 4; ++i)
#pragma unroll
            for (int j = 0; j < 4; ++j)
                acc[i][j] = __builtin_amdgcn_mfma_f32_16x16x32_bf16(
                    af[i], bg[j], acc[i][j], 0, 0, 0);
    }
    __syncthreads();   // all tile reads done; safe to reuse LDS

    // ---- epilogue: register partials -> LDS transpose -> atomics ----
    unsigned laMask = 0;
#pragma unroll
    for (int i = 0; i < 4; ++i)
#pragma unroll
        for (int r = 0; r < 4; ++r)
            if (target[row0 + wm + i * 16 + quad * 4 + r] == cls)
                laMask |= 1u << (i * 4 + r);
    int lb[4];
#pragma unroll
    for (int j = 0; j < 4; ++j) lb[j] = (target[col0 + wn + j * 16 + tx] == cls);

    float2* rbuf = (float2*)smem;                    // [wid][64 x17][tx] 34816 B
    float2* cbuf = (float2*)(smem + 17408);          // [wid][64 x5][quad] 10240 B
    // finalize scratch aliased beyond rbuf+cbuf (45056 B):
    int*   chist  = (int*)(smem + 23040);            // 40 ints  @46080
    float* wred   = (float*)(smem + 23168);          // 4 floats @46336
    int*   lastFl = (int*)(smem + 23176);            // 1 int    @46352
    float2 pcol[4] = {};

#pragma unroll
    for (int i = 0; i < 4; ++i) {
        float2 prow[4] = {};
#pragma unroll
        for (int j = 0; j < 4; ++j) {
            int cg = col0 + wn + j * 16 + tx;
            int lbj = lb[j];
#pragma unroll
            for (int r = 0; r < 4; ++r) {
                int rg = row0 + wm + i * 16 + quad * 4 + r;
                float logit = acc[i][j][r] * INV_T;
                float e = __expf(logit);
                bool dg = isDiag && (cg == rg);
                e = dg ? 0.0f : e;
                bool same = (((laMask >> (i * 4 + r)) & 1) == (unsigned)lbj) && !dg;
                float sl = same ? logit : 0.0f;
                prow[r].x += e; prow[r].y += sl;
                pcol[j].x += e; pcol[j].y += sl;
            }
        }
#pragma unroll
        for (int r = 0; r < 4; ++r)
            rbuf[wid * 1088 + (i * 16 + quad * 4 + r) * 17 + tx] = prow[r];
    }
#pragma unroll
    for (int j = 0; j < 4; ++j)
        cbuf[wid * 320 + (j * 16 + tx) * 5 + quad] = pcol[j];
    __syncthreads();

    if (t < 128) {
        // rows: wids 2*grp, 2*grp+1 share wm = 64*grp
        int rl = t & 63, grp = t >> 6;
        float den = 0.0f, sp = 0.0f;
#pragma unroll
        for (int w = 0; w < 2; ++w) {
            int base = (2 * grp + w) * 1088 + rl * 17;
#pragma unroll
            for (int x = 0; x < 16; ++x) {
                float2 v = rbuf[base + x];
                den += v.x; sp += v.y;
            }
        }
        atomicAdd(&denom[cls * BATCH + row0 + t], den);
        atomicAdd(&s2   [cls * BATCH + row0 + t], sp);
    } else if (!isDiag) {
        // cols: wids grp, grp+2 share wn = 64*grp
        int u = t - 128;
        int cl = u & 63, grp = u >> 6;
        float den = 0.0f, sp = 0.0f;
#pragma unroll
        for (int w = 0; w < 2; ++w) {
            int base = (grp + 2 * w) * 320 + cl * 5;
#pragma unroll
            for (int q = 0; q < 4; ++q) {
                float2 v = cbuf[base + q];
                den += v.x; sp += v.y;
            }
        }
        atomicAdd(&denom[cls * BATCH + col0 + u], den);
        atomicAdd(&s2   [cls * BATCH + col0 + u], sp);
    }

    // ---- fused finalize: last block reduces denom/s2 -> out ----
    // Release: this barrier drains every thread's global atomics
    // (__syncthreads emits s_waitcnt vmcnt(0) before s_barrier).
    __syncthreads();
    if (t == 0) {
        int old = atomicAdd(counter, 1);
        *lastFl = (old == NPAIR * NUM_CLASSES - 1);
    }
    __syncthreads();
    if (!*lastFl) return;
    __threadfence();   // acquire (single block only): invalidate stale caches

    // per-class histogram of target (each thread covers 8 entries)
    int hist[NUM_CLASSES];
#pragma unroll
    for (int c = 0; c < NUM_CLASSES; ++c) hist[c] = 0;
#pragma unroll
    for (int k = 0; k < 8; ++k) ++hist[target[t * 8 + k]];
#pragma unroll
    for (int c = 0; c < NUM_CLASSES; ++c) {
        int v = hist[c];
#pragma unroll
        for (int m = 1; m < 64; m <<= 1) v += __shfl_xor(v, m, 64);
        if (lane == 0) chist[c * 4 + wid] = v;
    }
    __syncthreads();

    float part = 0.0f;
    for (int idx = t; idx < NUM_CLASSES * BATCH; idx += 256) {
        int c2 = idx >> 11;
        int a  = idx & (BATCH - 1);
        int c1 = chist[c2 * 4] + chist[c2 * 4 + 1] + chist[c2 * 4 + 2] + chist[c2 * 4 + 3];
        int la = (target[a] == c2);
        int cnt = la ? (c1 - 1) : (BATCH - c1 - 1);
        float mlpp = s2[idx] / (float)cnt - logf(denom[idx]);
        part += __expf(-log_vars[c2]) * mlpp;
    }
#pragma unroll
    for (int m = 32; m; m >>= 1) part += __shfl_xor(part, m, 64);
    if (lane == 0) wred[wid] = part;
    __syncthreads();
    if (t == 0) {
        float lv = 0.0f;
        for (int i = 0; i < NUM_CLASSES; ++i) lv += log_vars[i];
        out[0] = lv - (wred[0] + wred[1] + wred[2] + wred[3]) / (float)BATCH;
    }
}

// ---------------------------------------------------------------------------
extern "C" void kernel_launch(void* const* d_in, const int* in_sizes, int n_in,
                              void* d_out, int out_size, void* d_ws, size_t ws_size,
                              hipStream_t stream)
{
    const float* preds    = (const float*)d_in[0];   // [10,2048,128] f32
    const int*   target   = (const int*)  d_in[1];   // [2048]
    const float* log_vars = (const float*)d_in[2];   // [10]
    float* out = (float*)d_out;

    __hip_bfloat16* gbf = (__hip_bfloat16*)d_ws;              // 10*2048*128 bf16
    float* denom  = (float*)((char*)d_ws + (size_t)NUM_CLASSES * BATCH * DIM * 2);
    float* s2     = denom + (size_t)NUM_CLASSES * BATCH;
    int*   counter = (int*)(s2 + (size_t)NUM_CLASSES * BATCH);

    normalize_kernel<<<NUM_CLASSES * BATCH / 4, 256, 0, stream>>>(
        preds, gbf, denom, counter);
    gram_kernel<<<dim3(NPAIR, NUM_CLASSES), 256, 0, stream>>>(
        gbf, target, denom, s2, counter, log_vars, out);
}